// Round 3
// baseline (253.644 us; speedup 1.0000x reference)
//
#include <hip/hip_runtime.h>

// OFT block-diagonal rotation (Cayley-Neumann, 5 terms).
// x: [8192, 4096] fp32, weight: [64, 2016] fp32 -> out: [8192, 4096] fp32.
// BLOCK = 64, R = 64.
//
// Strategy: rot built in fp32, emitted as bf16 hi/lo MFMA B-fragments.
// Apply = block-diag GEMM on matrix cores via split-bf16 3-pass
// (Ah*Bh + Ah*Bl + Al*Bh), fp32 accumulate -> ~1e-4 absmax, memory-bound.

#define NELEM 2016

typedef __attribute__((ext_vector_type(8))) short bfrag8;  // 8 bf16 = 4 VGPR
typedef __attribute__((ext_vector_type(4))) float f32x4;   // C/D accumulator

__device__ __forceinline__ int triu_off(int i) {
    return i * 63 - (i * (i - 1)) / 2;
}

__device__ __forceinline__ float skew_val(const float* __restrict__ wr, int i, int j) {
    if (i < j) return  wr[triu_off(i) + (j - i - 1)];
    if (i > j) return -wr[triu_off(j) + (i - j - 1)];
    return 0.f;
}

// split fp32 -> hi (truncated bf16) + lo (RNE bf16 of residual); hi+lo carries
// ~17 mantissa bits, residual error ~2^-17 relative.
__device__ __forceinline__ void bsplit(float v, short& h, short& l) {
    const unsigned u = __float_as_uint(v);
    h = (short)(u >> 16);
    const float resid = v - __uint_as_float(u & 0xffff0000u);
    const unsigned ur = __float_as_uint(resid);
    l = (short)((ur + 0x7fffu + ((ur >> 16) & 1u)) >> 16);
}

// Kernel 1: rot = I + 2Q + 2Q^2 + 2Q^3 + 2Q^4 (fp32 chain, matches reference),
// written as bf16 hi/lo B-fragments for mfma_f32_16x16x32_bf16:
//   frag[r][ct][s][lane][j] = rot[k = s*32 + (lane>>4)*8 + j][c = ct*16 + (lane&15)]
// Grid (r=64, row-tile=4), 256 threads; WG owns 16 rows of the power chain.
__global__ __launch_bounds__(256) void oft_rot_kernel(const float* __restrict__ w,
                                                      unsigned short* __restrict__ bh,
                                                      unsigned short* __restrict__ bl) {
    __shared__ float Q[64][64];        // 16 KB
    __shared__ float Pl[2][16][65];    // padded: conflict-free row reads

    const int r    = blockIdx.x;
    const int tile = blockIdx.y;                 // 0..3
    const float* __restrict__ wr = w + r * NELEM;
    const int tid = threadIdx.x;
    const int il  = tid >> 4;                    // 0..15 local row
    const int j0  = (tid & 15) << 2;             // col 0,4,...,60
    const int gi  = tile * 16 + il;              // global row 0..63

#pragma unroll
    for (int m = 0; m < 4; ++m) {
        const int i = il + 16 * m;
#pragma unroll
        for (int t = 0; t < 4; ++t)
            Q[i][j0 + t] = skew_val(wr, i, j0 + t);
    }
    __syncthreads();

    float racc[4];
#pragma unroll
    for (int t = 0; t < 4; ++t) {
        const float qv = Q[gi][j0 + t];
        Pl[0][il][j0 + t] = qv;
        racc[t] = (gi == j0 + t ? 1.f : 0.f) + 2.f * qv;
    }
    __syncthreads();

    int cur = 0;
#pragma unroll
    for (int p = 2; p < 5; ++p) {
        float a0 = 0.f, a1 = 0.f, a2 = 0.f, a3 = 0.f;
#pragma unroll 8
        for (int k = 0; k < 64; ++k) {
            const float  pv = Pl[cur][il][k];
            const float4 qv = *(const float4*)&Q[k][j0];
            a0 = fmaf(pv, qv.x, a0);
            a1 = fmaf(pv, qv.y, a1);
            a2 = fmaf(pv, qv.z, a2);
            a3 = fmaf(pv, qv.w, a3);
        }
        Pl[cur ^ 1][il][j0 + 0] = a0;
        Pl[cur ^ 1][il][j0 + 1] = a1;
        Pl[cur ^ 1][il][j0 + 2] = a2;
        Pl[cur ^ 1][il][j0 + 3] = a3;
        racc[0] += 2.f * a0;
        racc[1] += 2.f * a1;
        racc[2] += 2.f * a2;
        racc[3] += 2.f * a3;
        __syncthreads();
        cur ^= 1;
    }

    // emit hi/lo fragments: this thread owns rot[gi][j0..j0+3]
    const int s    = gi >> 5;
    const int jj   = gi & 7;
    const int lhi  = ((gi >> 3) & 3) << 4;       // lane bits 4..5 from k
#pragma unroll
    for (int t = 0; t < 4; ++t) {
        const int j    = j0 + t;
        const int ct   = j >> 4;
        const int lane = lhi + (j & 15);
        const int off  = (((r * 4 + ct) * 2 + s) * 64 + lane) * 8 + jj;
        short h, l;
        bsplit(racc[t], h, l);
        bh[off] = (unsigned short)h;
        bl[off] = (unsigned short)l;
    }
}

// Kernel 2: out[n, r*64+c] = sum_k x[n, r*64+k] * rot[r][k][c] on matrix cores.
// Wave computes 16 tokens x 64 cols per tile; 4 waves/WG -> 64-token tiles;
// each WG loops 4 tiles with B-frags resident in VGPRs. No LDS.
// A-frag (16x32): lane l -> row = l&15, k = (l>>4)*8 + j  (two float4 per kstep)
// B-frag (32x16): lane l -> col = l&15, k = (l>>4)*8 + j  (precomputed in ws)
// C/D:            lane l -> col = l&15, row = (l>>4)*4 + q  [m89 verified]
__global__ __launch_bounds__(256) void oft_apply_kernel(const float* __restrict__ x,
                                                        const unsigned short* __restrict__ bh,
                                                        const unsigned short* __restrict__ bl,
                                                        float* __restrict__ out) {
    const int tid  = threadIdx.x;
    const int w    = tid >> 6;
    const int l    = tid & 63;
    const int lrow = l & 15;
    const int lk   = l >> 4;
    const int r     = blockIdx.x;                // 0..63
    const int chunk = blockIdx.y;                // 0..31 -> 4 tiles of 64 tokens

    // preload all B fragments for this r (64 VGPRs)
    bfrag8 Bh[4][2], Bl[4][2];
#pragma unroll
    for (int ct = 0; ct < 4; ++ct)
#pragma unroll
        for (int s = 0; s < 2; ++s) {
            const int off = (((r * 4 + ct) * 2 + s) * 64 + l) * 8;
            Bh[ct][s] = *(const bfrag8*)(bh + off);
            Bl[ct][s] = *(const bfrag8*)(bl + off);
        }

#pragma unroll
    for (int tt = 0; tt < 4; ++tt) {
        const int tokbase = (chunk * 4 + tt) * 64 + w * 16;
        const float* __restrict__ xp =
            x + (size_t)(tokbase + lrow) * 4096 + r * 64 + lk * 8;

        const f32x4 a0 = *(const f32x4*)(xp);        // s=0, j=0..3
        const f32x4 a1 = *(const f32x4*)(xp + 4);    // s=0, j=4..7
        const f32x4 a2 = *(const f32x4*)(xp + 32);   // s=1, j=0..3
        const f32x4 a3 = *(const f32x4*)(xp + 36);   // s=1, j=4..7

        bfrag8 Ah0, Al0, Ah1, Al1;
#pragma unroll
        for (int j = 0; j < 4; ++j) {
            short h, lo;
            bsplit(a0[j], h, lo); Ah0[j]     = h; Al0[j]     = lo;
            bsplit(a1[j], h, lo); Ah0[4 + j] = h; Al0[4 + j] = lo;
            bsplit(a2[j], h, lo); Ah1[j]     = h; Al1[j]     = lo;
            bsplit(a3[j], h, lo); Ah1[4 + j] = h; Al1[4 + j] = lo;
        }

        f32x4 acc[4];
#pragma unroll
        for (int ct = 0; ct < 4; ++ct) {
            acc[ct] = (f32x4)(0.f);
            acc[ct] = __builtin_amdgcn_mfma_f32_16x16x32_bf16(Al0, Bh[ct][0], acc[ct], 0, 0, 0);
            acc[ct] = __builtin_amdgcn_mfma_f32_16x16x32_bf16(Ah0, Bl[ct][0], acc[ct], 0, 0, 0);
            acc[ct] = __builtin_amdgcn_mfma_f32_16x16x32_bf16(Ah0, Bh[ct][0], acc[ct], 0, 0, 0);
            acc[ct] = __builtin_amdgcn_mfma_f32_16x16x32_bf16(Al1, Bh[ct][1], acc[ct], 0, 0, 0);
            acc[ct] = __builtin_amdgcn_mfma_f32_16x16x32_bf16(Ah1, Bl[ct][1], acc[ct], 0, 0, 0);
            acc[ct] = __builtin_amdgcn_mfma_f32_16x16x32_bf16(Ah1, Bh[ct][1], acc[ct], 0, 0, 0);
        }

        // store: lane l holds rows lk*4+q, col lrow of each 16-col tile ct
        const size_t obase = (size_t)(tokbase + lk * 4) * 4096 + r * 64 + lrow;
#pragma unroll
        for (int ct = 0; ct < 4; ++ct)
#pragma unroll
            for (int q = 0; q < 4; ++q)
                out[obase + (size_t)q * 4096 + ct * 16] = acc[ct][q];
    }
}

extern "C" void kernel_launch(void* const* d_in, const int* in_sizes, int n_in,
                              void* d_out, int out_size, void* d_ws, size_t ws_size,
                              hipStream_t stream) {
    const float* x = (const float*)d_in[0];   // [8192, 4096]
    const float* w = (const float*)d_in[1];   // [64, 2016]
    float* out = (float*)d_out;               // [8192, 4096]

    // ws: bf16 hi/lo B-fragments, 512 KB each
    unsigned short* bh = (unsigned short*)d_ws;
    unsigned short* bl = bh + 64 * 4 * 2 * 64 * 8;

    oft_rot_kernel<<<dim3(64, 4), 256, 0, stream>>>(w, bh, bl);
    oft_apply_kernel<<<dim3(64, 32), 256, 0, stream>>>(x, bh, bl, out);
}